// Round 3
// baseline (531.425 us; speedup 1.0000x reference)
//
#include <hip/hip_runtime.h>
#include <math.h>

// CosFace-style loss, two-phase:
//  K1: grid = B*SPLIT blocks; each block sums exp(64*x) over a C/SPLIT chunk
//      of one row (fp32 per-thread acc -> fp64 block reduce) -> ws partials.
//  K2: one block; per-row combine partials + margin/log in fp64, mean, negate.
// Memory-bound: 400 MB read, roofline ~64 us @ 6.3 TB/s.
// NOTE: __exp2f collides with glibc math.h internals — use the amdgcn builtin.

#define SPLIT 8
#define EXP2(v) __builtin_amdgcn_exp2f(v)

__device__ __forceinline__ double block_reduce_d(double v) {
    #pragma unroll
    for (int off = 32; off > 0; off >>= 1) v += __shfl_down(v, off, 64);
    __shared__ double s[4];
    const int lane = threadIdx.x & 63;
    const int w    = threadIdx.x >> 6;
    if (lane == 0) s[w] = v;
    __syncthreads();
    if (w == 0) {
        v = (lane < 4) ? s[lane] : 0.0;
        v += __shfl_down(v, 2, 64);
        v += __shfl_down(v, 1, 64);
    }
    return v;  // valid in thread 0
}

__global__ __launch_bounds__(256) void partial_sum_kernel(
    const float* __restrict__ x, double* __restrict__ partials,
    int C, int chunk)
{
    const int row  = blockIdx.x / SPLIT;
    const int ch   = blockIdx.x - row * SPLIT;
    const long off = (long)ch * chunk;
    int n = C - (int)off;
    if (n > chunk) n = chunk;
    const int tid = threadIdx.x;
    const float K2 = 92.33248261689366f;  // 64 / ln(2): exp(64x) = exp2(K2*x)

    float acc = 0.0f;
    if (n > 0) {
        const float* __restrict__ xp = x + (long)row * C + off;
        const int n4 = n >> 2;
        const float4* __restrict__ x4 = (const float4*)xp;  // chunk%4==0 -> aligned

        int v = tid;
        for (; v + 3 * 256 < n4; v += 4 * 256) {
            float4 a = x4[v];
            float4 b = x4[v + 256];
            float4 c = x4[v + 512];
            float4 d = x4[v + 768];
            float s0 = EXP2(K2 * a.x) + EXP2(K2 * a.y) +
                       EXP2(K2 * a.z) + EXP2(K2 * a.w);
            float s1 = EXP2(K2 * b.x) + EXP2(K2 * b.y) +
                       EXP2(K2 * b.z) + EXP2(K2 * b.w);
            float s2 = EXP2(K2 * c.x) + EXP2(K2 * c.y) +
                       EXP2(K2 * c.z) + EXP2(K2 * c.w);
            float s3 = EXP2(K2 * d.x) + EXP2(K2 * d.y) +
                       EXP2(K2 * d.z) + EXP2(K2 * d.w);
            acc += (s0 + s1) + (s2 + s3);
        }
        for (; v < n4; v += 256) {
            float4 a = x4[v];
            acc += EXP2(K2 * a.x) + EXP2(K2 * a.y) +
                   EXP2(K2 * a.z) + EXP2(K2 * a.w);
        }
        for (int j = (n4 << 2) + tid; j < n; j += 256)
            acc += EXP2(K2 * xp[j]);
    }

    double total = block_reduce_d((double)acc);
    if (tid == 0) partials[(long)row * SPLIT + ch] = total;
}

__global__ __launch_bounds__(256) void finalize_kernel(
    const float* __restrict__ x, const int* __restrict__ label,
    const double* __restrict__ partials, float* __restrict__ out,
    int B, int C)
{
    double acc = 0.0;
    for (int r = threadIdx.x; r < B; r += 256) {
        double s = 0.0;
        #pragma unroll
        for (int c = 0; c < SPLIT; ++c) s += partials[(long)r * SPLIT + c];
        const double xy  = (double)x[(long)r * C + label[r]];
        const double num = 64.0 * (xy - 0.35);
        const double exy = exp(64.0 * xy);
        const double denom = exp(num) + (s - exy);   // fp64: cancellation-safe
        acc += (num - log(denom)) * (1.0 / 64.0);
    }
    double total = block_reduce_d(acc);
    if (threadIdx.x == 0) out[0] = (float)(-total / (double)B);
}

extern "C" void kernel_launch(void* const* d_in, const int* in_sizes, int n_in,
                              void* d_out, int out_size, void* d_ws, size_t ws_size,
                              hipStream_t stream) {
    const float* x     = (const float*)d_in[0];
    const int*   label = (const int*)d_in[1];
    const int B = in_sizes[1];
    const int C = in_sizes[0] / B;

    // chunk: ceil(C/SPLIT) rounded up to a multiple of 4 (keeps float4 alignment)
    int chunk = (C + SPLIT - 1) / SPLIT;
    chunk = (chunk + 3) & ~3;

    double* partials = (double*)d_ws;  // B*SPLIT doubles = 64 KB

    partial_sum_kernel<<<B * SPLIT, 256, 0, stream>>>(x, partials, C, chunk);
    finalize_kernel<<<1, 256, 0, stream>>>(x, label, partials, (float*)d_out, B, C);
}